// Round 2
// baseline (4948.049 us; speedup 1.0000x reference)
//
#include <hip/hip_runtime.h>
#include <math.h>
#include <stdint.h>

// ---------------------------------------------------------------------------
// BasicTransformerBlock (B=2, H=W=64, C=320) fp32 baseline.
// x2 = 2x + selfattn(x);  xn = GN(x2);  x3 = xn + crossattn(xn, ctx) + x2
// ff = geglu(x3);  out = ff @ Wd + bd + x3
// Workspace layout (floats), SZ = 8192*320:
//   [0,SZ)   x2   [SZ,2SZ) xn   [2SZ,3SZ) q   [3SZ,4SZ) k
//   [4SZ,5SZ) v   [5SZ,6SZ) o   [6SZ, 6SZ+CH*Nn) S   then stats(512)
//   x3 aliases S (dead after attn2); ff aliases q..o (4*SZ, dead after x3).
// ---------------------------------------------------------------------------

constexpr int Bb = 2, Hh = 64, Ww = 64, Cc = 320;
constexpr int Nn = Hh * Ww;          // 4096 tokens per batch
constexpr int Mm = Bb * Nn;          // 8192 total rows
constexpr int GROUPS = 16, CG = Cc / GROUPS;  // 20
constexpr float EPS = 1e-3f;
constexpr int CH = 1024;             // S-chunk rows (16.8 MB scratch)
constexpr int GN_SPLIT = 8;

// ---------------- generic tiled SGEMM: C = scale*(A@B) + bias + a1*R1 + R2 --
// A: [M,K] lda, row-major.  BT=false: B[K,N] ldb.  BT=true: B[N,K] ldb (NT).
// grid = (N/64, M/64), 256 threads, 4x4 micro-tile.
template <bool BT>
__global__ __launch_bounds__(256) void sgemm_k(
    const float* __restrict__ A, int lda,
    const float* __restrict__ B, int ldb,
    const float* __restrict__ bias,
    const float* __restrict__ R1, float alpha1,
    const float* __restrict__ R2,
    float* __restrict__ C, int ldc,
    int K, float scale) {
  __shared__ float As[16][64];
  __shared__ float Bs[16][64];
  const int tid  = threadIdx.x;
  const int bm   = blockIdx.y * 64;
  const int bn   = blockIdx.x * 64;
  const int arow = tid >> 2;          // 0..63
  const int ak   = (tid & 3) << 2;    // 0,4,8,12
  const int tr   = (tid >> 4) << 2;   // 0..60
  const int tc   = (tid & 15) << 2;   // 0..60

  float acc[4][4] = {};

  for (int k0 = 0; k0 < K; k0 += 16) {
    // stage A tile (64 rows x 16 k), transposed into As[k][m]
    {
      const float4 av = *reinterpret_cast<const float4*>(
          A + (size_t)(bm + arow) * lda + k0 + ak);
      As[ak + 0][arow] = av.x;
      As[ak + 1][arow] = av.y;
      As[ak + 2][arow] = av.z;
      As[ak + 3][arow] = av.w;
    }
    if (BT) {
      // B logical [K][N] from Bmat[n*ldb + k]
      const float4 bv = *reinterpret_cast<const float4*>(
          B + (size_t)(bn + arow) * ldb + k0 + ak);
      Bs[ak + 0][arow] = bv.x;
      Bs[ak + 1][arow] = bv.y;
      Bs[ak + 2][arow] = bv.z;
      Bs[ak + 3][arow] = bv.w;
    } else {
      const int kr = tid >> 4;          // 0..15
      const int bc = (tid & 15) << 2;   // 0..60
      *reinterpret_cast<float4*>(&Bs[kr][bc]) =
          *reinterpret_cast<const float4*>(B + (size_t)(k0 + kr) * ldb + bn + bc);
    }
    __syncthreads();

#pragma unroll
    for (int kk = 0; kk < 16; ++kk) {
      const float4 a4 = *reinterpret_cast<const float4*>(&As[kk][tr]);
      const float4 b4 = *reinterpret_cast<const float4*>(&Bs[kk][tc]);
      const float a[4] = {a4.x, a4.y, a4.z, a4.w};
      const float b[4] = {b4.x, b4.y, b4.z, b4.w};
#pragma unroll
      for (int i = 0; i < 4; ++i)
#pragma unroll
        for (int j = 0; j < 4; ++j) acc[i][j] += a[i] * b[j];
    }
    __syncthreads();
  }

#pragma unroll
  for (int i = 0; i < 4; ++i) {
    const size_t row = bm + tr + i;
#pragma unroll
    for (int j = 0; j < 4; ++j) {
      const int col = bn + tc + j;
      float v = acc[i][j] * scale;
      if (bias) v += bias[col];
      if (R1) v += alpha1 * R1[row * ldc + col];
      if (R2) v += R2[row * ldc + col];
      C[row * ldc + col] = v;
    }
  }
}

// ---------------- row softmax over 4096 cols, in place ----------------------
__global__ __launch_bounds__(256) void softmax_rows(float* __restrict__ S) {
  float* p = S + (size_t)blockIdx.x * Nn;
  const int tid = threadIdx.x;
  float vals[16];
  float m = -INFINITY;
#pragma unroll
  for (int i = 0; i < 16; ++i) {
    vals[i] = p[tid + i * 256];
    m = fmaxf(m, vals[i]);
  }
#pragma unroll
  for (int off = 32; off >= 1; off >>= 1) m = fmaxf(m, __shfl_xor(m, off, 64));
  __shared__ float red[8];
  if ((tid & 63) == 0) red[tid >> 6] = m;
  __syncthreads();
  m = fmaxf(fmaxf(red[0], red[1]), fmaxf(red[2], red[3]));

  float s = 0.f;
#pragma unroll
  for (int i = 0; i < 16; ++i) {
    vals[i] = __expf(vals[i] - m);
    s += vals[i];
  }
#pragma unroll
  for (int off = 32; off >= 1; off >>= 1) s += __shfl_xor(s, off, 64);
  if ((tid & 63) == 0) red[4 + (tid >> 6)] = s;
  __syncthreads();
  s = red[4] + red[5] + red[6] + red[7];
  const float inv = 1.0f / s;
#pragma unroll
  for (int i = 0; i < 16; ++i) p[tid + i * 256] = vals[i] * inv;
}

// ---------------- GroupNorm: partial stats then apply -----------------------
// grid = B*GROUPS*GN_SPLIT. partials[(bg*GN_SPLIT+s)*2 + {0,1}] = {sum, sumsq}
__global__ __launch_bounds__(256) void gn_stats(const float* __restrict__ x,
                                                float* __restrict__ partials) {
  const int s  = blockIdx.x % GN_SPLIT;
  const int bg = blockIdx.x / GN_SPLIT;
  const int b  = bg / GROUPS, g = bg % GROUPS;
  const int rows = Nn / GN_SPLIT;  // 512
  const float* base = x + (size_t)b * Nn * Cc + g * CG;
  float sum = 0.f, sq = 0.f;
  for (int i = threadIdx.x; i < rows * CG; i += 256) {
    const int r = i / CG, c = i % CG;
    const float v = base[(size_t)(s * rows + r) * Cc + c];
    sum += v;
    sq += v * v;
  }
#pragma unroll
  for (int off = 32; off >= 1; off >>= 1) {
    sum += __shfl_xor(sum, off, 64);
    sq += __shfl_xor(sq, off, 64);
  }
  __shared__ float rs[4], rq[4];
  const int tid = threadIdx.x;
  if ((tid & 63) == 0) {
    rs[tid >> 6] = sum;
    rq[tid >> 6] = sq;
  }
  __syncthreads();
  if (tid == 0) {
    sum = rs[0] + rs[1] + rs[2] + rs[3];
    sq  = rq[0] + rq[1] + rq[2] + rq[3];
    partials[(bg * GN_SPLIT + s) * 2 + 0] = sum;
    partials[(bg * GN_SPLIT + s) * 2 + 1] = sq;
  }
}

__global__ __launch_bounds__(256) void gn_apply(
    const float* __restrict__ x, const float* __restrict__ partials,
    const float* __restrict__ gamma, const float* __restrict__ beta,
    float* __restrict__ xn) {
  const size_t idx = (size_t)blockIdx.x * 256 + threadIdx.x;  // < Mm*Cc
  const int c = (int)(idx % Cc);
  const size_t row = idx / Cc;
  const int b = (int)(row / Nn);
  const int g = c / CG;
  const int bg = b * GROUPS + g;
  float sum = 0.f, sq = 0.f;
#pragma unroll
  for (int s = 0; s < GN_SPLIT; ++s) {
    sum += partials[(bg * GN_SPLIT + s) * 2 + 0];
    sq  += partials[(bg * GN_SPLIT + s) * 2 + 1];
  }
  const float cnt = (float)Nn * CG;  // 81920
  const float mean = sum / cnt;
  const float var = sq / cnt - mean * mean;
  const float r = rsqrtf(var + EPS);
  xn[idx] = (x[idx] - mean) * r * gamma[c] + beta[c];
}

// ---------------- GEGLU: ff = (X@W[:, :4C]+b1) * qgelu(X@W[:, 4C:]+b2) ------
// grid = (1280/64, M/64)
__global__ __launch_bounds__(256) void geglu_k(
    const float* __restrict__ A, int lda,        // x3 [M,320]
    const float* __restrict__ B, int ldb,        // geglu_w [320,2560]
    const float* __restrict__ bias,              // [2560]
    float* __restrict__ FF, int ldf) {           // [M,1280]
  __shared__ float As[16][64];
  __shared__ float B1s[16][64];
  __shared__ float B2s[16][64];
  const int tid  = threadIdx.x;
  const int bm   = blockIdx.y * 64;
  const int bn   = blockIdx.x * 64;
  const int arow = tid >> 2;
  const int ak   = (tid & 3) << 2;
  const int kr   = tid >> 4;
  const int bc   = (tid & 15) << 2;
  const int tr   = (tid >> 4) << 2;
  const int tc   = (tid & 15) << 2;
  float acc1[4][4] = {}, acc2[4][4] = {};

  for (int k0 = 0; k0 < Cc; k0 += 16) {
    const float4 av = *reinterpret_cast<const float4*>(
        A + (size_t)(bm + arow) * lda + k0 + ak);
    As[ak + 0][arow] = av.x;
    As[ak + 1][arow] = av.y;
    As[ak + 2][arow] = av.z;
    As[ak + 3][arow] = av.w;
    *reinterpret_cast<float4*>(&B1s[kr][bc]) =
        *reinterpret_cast<const float4*>(B + (size_t)(k0 + kr) * ldb + bn + bc);
    *reinterpret_cast<float4*>(&B2s[kr][bc]) =
        *reinterpret_cast<const float4*>(B + (size_t)(k0 + kr) * ldb + 1280 + bn + bc);
    __syncthreads();
#pragma unroll
    for (int kk = 0; kk < 16; ++kk) {
      const float4 a4  = *reinterpret_cast<const float4*>(&As[kk][tr]);
      const float4 b14 = *reinterpret_cast<const float4*>(&B1s[kk][tc]);
      const float4 b24 = *reinterpret_cast<const float4*>(&B2s[kk][tc]);
      const float a[4]  = {a4.x, a4.y, a4.z, a4.w};
      const float b1[4] = {b14.x, b14.y, b14.z, b14.w};
      const float b2[4] = {b24.x, b24.y, b24.z, b24.w};
#pragma unroll
      for (int i = 0; i < 4; ++i)
#pragma unroll
        for (int j = 0; j < 4; ++j) {
          acc1[i][j] += a[i] * b1[j];
          acc2[i][j] += a[i] * b2[j];
        }
    }
    __syncthreads();
  }

#pragma unroll
  for (int i = 0; i < 4; ++i) {
    const size_t row = bm + tr + i;
#pragma unroll
    for (int j = 0; j < 4; ++j) {
      const int col = bn + tc + j;
      const float v1 = acc1[i][j] + bias[col];
      const float v2 = acc2[i][j] + bias[col + 1280];
      const float g = v2 / (1.0f + __expf(-1.702f * v2));  // quick_gelu
      FF[row * ldf + col] = v1 * g;
    }
  }
}

// ---------------------------------------------------------------------------
extern "C" void kernel_launch(void* const* d_in, const int* in_sizes, int n_in,
                              void* d_out, int out_size, void* d_ws,
                              size_t ws_size, hipStream_t stream) {
  const float* x      = (const float*)d_in[0];
  const float* ctx    = (const float*)d_in[1];
  const float* sa_q_w = (const float*)d_in[2];
  const float* sa_q_b = (const float*)d_in[3];
  const float* sa_k_w = (const float*)d_in[4];
  const float* sa_k_b = (const float*)d_in[5];
  const float* sa_v_w = (const float*)d_in[6];
  const float* sa_v_b = (const float*)d_in[7];
  const float* sa_p_w = (const float*)d_in[8];
  const float* sa_p_b = (const float*)d_in[9];
  const float* ca_q_w = (const float*)d_in[10];
  const float* ca_q_b = (const float*)d_in[11];
  const float* ca_k_w = (const float*)d_in[12];
  const float* ca_k_b = (const float*)d_in[13];
  const float* ca_v_w = (const float*)d_in[14];
  const float* ca_v_b = (const float*)d_in[15];
  const float* ca_p_w = (const float*)d_in[16];
  const float* ca_p_b = (const float*)d_in[17];
  const float* gn_g   = (const float*)d_in[18];
  const float* gn_b   = (const float*)d_in[19];
  const float* gw     = (const float*)d_in[20];
  const float* gb     = (const float*)d_in[21];
  const float* dw     = (const float*)d_in[22];
  const float* db     = (const float*)d_in[23];
  float* out = (float*)d_out;

  float* ws = (float*)d_ws;
  const size_t SZ = (size_t)Mm * Cc;  // 2,621,440
  float* x2 = ws;
  float* xn = ws + SZ;
  float* q  = ws + 2 * SZ;
  float* k  = ws + 3 * SZ;
  float* v  = ws + 4 * SZ;
  float* o  = ws + 5 * SZ;
  float* S  = ws + 6 * SZ;                    // CH*Nn floats
  float* stats = S + (size_t)CH * Nn;         // 512 floats
  float* x3 = S;  // alias: S dead after attn2 (needs CH*Nn >= SZ: 4.19M >= 2.62M)
  float* ff = q;  // alias q..o (4*SZ), dead once x3 is computed; ff needs 4*SZ

  const size_t need = (6 * SZ + (size_t)CH * Nn + 1024) * sizeof(float);
  if (ws == nullptr || ws_size < need) return;  // d_out stays poisoned -> visible failure

  const float scale = 1.0f / sqrtf((float)Cc);

  auto gemm = [&](bool bt, const float* A, int lda, const float* B, int ldb,
                  const float* bias, const float* R1, float al1,
                  const float* R2, float* C, int ldc, int Mr, int Nc, int K,
                  float sc) {
    dim3 grid(Nc / 64, Mr / 64);
    if (bt)
      sgemm_k<true><<<grid, 256, 0, stream>>>(A, lda, B, ldb, bias, R1, al1, R2, C, ldc, K, sc);
    else
      sgemm_k<false><<<grid, 256, 0, stream>>>(A, lda, B, ldb, bias, R1, al1, R2, C, ldc, K, sc);
  };

  auto attention = [&](const float* qsrc, const float* kvsrc,
                       const float* wq, const float* bq, const float* wk,
                       const float* bk, const float* wv, const float* bv) {
    gemm(false, qsrc, Cc, wq, Cc, bq, nullptr, 0.f, nullptr, q, Cc, Mm, Cc, Cc, 1.f);
    gemm(false, kvsrc, Cc, wk, Cc, bk, nullptr, 0.f, nullptr, k, Cc, Mm, Cc, Cc, 1.f);
    gemm(false, kvsrc, Cc, wv, Cc, bv, nullptr, 0.f, nullptr, v, Cc, Mm, Cc, Cc, 1.f);
    for (int b = 0; b < Bb; ++b)
      for (int ch = 0; ch < Nn / CH; ++ch) {
        const int row0 = b * Nn + ch * CH;
        // S = scale * q_chunk @ k_batch^T   [CH, Nn]
        gemm(true, q + (size_t)row0 * Cc, Cc, k + (size_t)b * Nn * Cc, Cc,
             nullptr, nullptr, 0.f, nullptr, S, Nn, CH, Nn, Cc, scale);
        softmax_rows<<<CH, 256, 0, stream>>>(S);
        // o_chunk = S @ v_batch            [CH, Cc]
        gemm(false, S, Nn, v + (size_t)b * Nn * Cc, Cc, nullptr, nullptr, 0.f,
             nullptr, o + (size_t)row0 * Cc, Cc, CH, Cc, Nn, 1.f);
      }
  };

  // ---- self-attention:  x2 = o@Wp + bp + 2*x
  attention(x, x, sa_q_w, sa_q_b, sa_k_w, sa_k_b, sa_v_w, sa_v_b);
  gemm(false, o, Cc, sa_p_w, Cc, sa_p_b, x, 2.0f, nullptr, x2, Cc, Mm, Cc, Cc, 1.f);

  // ---- GroupNorm(x2) -> xn
  gn_stats<<<Bb * GROUPS * GN_SPLIT, 256, 0, stream>>>(x2, stats);
  gn_apply<<<(int)((SZ) / 256), 256, 0, stream>>>(x2, stats, gn_g, gn_b, xn);

  // ---- cross-attention (q from xn, k/v from ctx); then x3 = o@Wp2 + bp2 + xn + x2
  attention(xn, ctx, ca_q_w, ca_q_b, ca_k_w, ca_k_b, ca_v_w, ca_v_b);
  gemm(false, o, Cc, ca_p_w, Cc, ca_p_b, xn, 1.0f, x2, x3, Cc, Mm, Cc, Cc, 1.f);

  // ---- GEGLU FFN: ff = geglu(x3);  out = ff @ dw + db + x3
  geglu_k<<<dim3(1280 / 64, Mm / 64), 256, 0, stream>>>(x3, Cc, gw, 8 * Cc, gb, ff, 4 * Cc);
  gemm(false, ff, 4 * Cc, dw, Cc, db, x3, 1.0f, nullptr, out, Cc, Mm, Cc, 4 * Cc, 1.f);
}

// Round 3
// 857.670 us; speedup vs baseline: 5.7692x; 5.7692x over previous
//
#include <hip/hip_runtime.h>
#include <math.h>
#include <stdint.h>

// ---------------------------------------------------------------------------
// BasicTransformerBlock (B=2, H=W=64, C=320) — bf16 MFMA version.
// All GEMMs: NT form (A[M][K] row-major bf16, B[N][K] row-major bf16),
// MFMA 16x16x32_bf16, fp32 accumulate, BM=128 BN=64 BK=32, 4 waves/block.
// x2 = 2x + selfattn(x);  xn = GN(x2);  x3 = xn + crossattn(xn,ctx) + x2
// ff = geglu(x3);  out = ff @ Wd + bd + x3
// ---------------------------------------------------------------------------

typedef unsigned short u16;
typedef __attribute__((ext_vector_type(8))) short bf16x8;
typedef __attribute__((ext_vector_type(8))) unsigned short u16x8;
typedef __attribute__((ext_vector_type(4))) float f32x4;

constexpr int Bb = 2, Cc = 320;
constexpr int Nn = 64 * 64;                    // 4096 tokens per batch
constexpr int Mm = Bb * Nn;                    // 8192 rows
constexpr int GROUPS = 16, CG = Cc / GROUPS;   // 20
constexpr float EPS = 1e-3f;
constexpr int CH = 2048;                       // q-chunk rows per S pass
constexpr int GN_SPLIT = 8;

__device__ __forceinline__ u16 f2b(float f) {
  unsigned u = __float_as_uint(f);
  unsigned r = u + 0x7fffu + ((u >> 16) & 1u);
  return (u16)(r >> 16);
}
__device__ __forceinline__ float b2f(u16 h) {
  return __uint_as_float(((unsigned)h) << 16);
}

// ---------------- bf16 NT GEMM with fused epilogue --------------------------
// C = scale*(A@B^T) + bias + alpha1*R1 + R2 ; C is fp32 (F32OUT) or bf16.
// DUAL additionally writes bf16 copy to C2. z = blockIdx.z batch slice.
template <bool F32OUT, bool DUAL>
__global__ __launch_bounds__(256) void gemm_nt(
    const u16* __restrict__ A, int lda, long long aZ,
    const u16* __restrict__ B, int ldb, long long bZ,
    const float* __restrict__ bias,
    const float* __restrict__ R1, float alpha1,
    const float* __restrict__ R2,
    void* __restrict__ Cp, int ldc, long long cZ,
    u16* __restrict__ C2,
    int K, float scale) {
  const int z = blockIdx.z;
  A += (long long)z * aZ;
  B += (long long)z * bZ;
  const long long coffz = (long long)z * cZ;

  __shared__ __align__(16) u16 As[128][40];  // +8 pad: breaks bank conflicts
  __shared__ __align__(16) u16 Bs[64][40];

  const int tid = threadIdx.x;
  const int bm = blockIdx.y * 128, bn = blockIdx.x * 64;
  const int lane = tid & 63;
  const int wid = tid >> 6;
  const int wm = (wid >> 1) * 64, wn = (wid & 1) * 32;  // wave sub-tile origin
  const int lr = lane & 15, lk = (lane >> 4) * 8;       // frag row/col, k-off

  const int sr = tid >> 2;        // staging row 0..63
  const int sk = (tid & 3) * 8;   // staging k offset

  f32x4 acc[4][2] = {};

  const u16* Ap0 = A + (size_t)(bm + sr) * lda + sk;
  const u16* Ap1 = A + (size_t)(bm + 64 + sr) * lda + sk;
  const u16* Bp0 = B + (size_t)(bn + sr) * ldb + sk;

  for (int k0 = 0; k0 < K; k0 += 32) {
    *reinterpret_cast<u16x8*>(&As[sr][sk]) =
        *reinterpret_cast<const u16x8*>(Ap0 + k0);
    *reinterpret_cast<u16x8*>(&As[64 + sr][sk]) =
        *reinterpret_cast<const u16x8*>(Ap1 + k0);
    *reinterpret_cast<u16x8*>(&Bs[sr][sk]) =
        *reinterpret_cast<const u16x8*>(Bp0 + k0);
    __syncthreads();

    bf16x8 af[4], bfr[2];
#pragma unroll
    for (int i = 0; i < 4; ++i)
      af[i] = *reinterpret_cast<const bf16x8*>(&As[wm + i * 16 + lr][lk]);
#pragma unroll
    for (int j = 0; j < 2; ++j)
      bfr[j] = *reinterpret_cast<const bf16x8*>(&Bs[wn + j * 16 + lr][lk]);
#pragma unroll
    for (int i = 0; i < 4; ++i)
#pragma unroll
      for (int j = 0; j < 2; ++j)
        acc[i][j] = __builtin_amdgcn_mfma_f32_16x16x32_bf16(af[i], bfr[j],
                                                            acc[i][j], 0, 0, 0);
    __syncthreads();
  }

  float* Cf = (float*)Cp;
  u16* Cb = (u16*)Cp;
#pragma unroll
  for (int i = 0; i < 4; ++i)
#pragma unroll
    for (int j = 0; j < 2; ++j)
#pragma unroll
      for (int r = 0; r < 4; ++r) {
        // verified C/D layout: col = lane&15, row = (lane>>4)*4 + reg
        const int row = bm + wm + i * 16 + (lane >> 4) * 4 + r;
        const int col = bn + wn + j * 16 + lr;
        const long long off = (long long)row * ldc + col + coffz;
        float v = acc[i][j][r] * scale;
        if (bias) v += bias[col];
        if (R1) v += alpha1 * R1[off];
        if (R2) v += R2[off];
        if (F32OUT) Cf[off] = v; else Cb[off] = f2b(v);
        if (DUAL) C2[off] = f2b(v);
      }
}

// ---------------- fp32 -> bf16 flat cast ------------------------------------
__global__ __launch_bounds__(256) void cast_b(const float* __restrict__ in,
                                              u16* __restrict__ out) {
  const size_t i = ((size_t)blockIdx.x * 256 + threadIdx.x) * 4;
  const float4 v = *reinterpret_cast<const float4*>(in + i);
  ushort4 o;
  o.x = f2b(v.x); o.y = f2b(v.y); o.z = f2b(v.z); o.w = f2b(v.w);
  *reinterpret_cast<ushort4*>(out + i) = o;
}

// ---------------- fp32 [R][C] -> bf16 [C][R] tiled transpose ----------------
__global__ __launch_bounds__(256) void tran_f2b(const float* __restrict__ in,
                                                u16* __restrict__ out, int R,
                                                int C, long long inZ,
                                                long long outZ) {
  in += (long long)blockIdx.z * inZ;
  out += (long long)blockIdx.z * outZ;
  __shared__ u16 t[32][33];
  const int c0 = blockIdx.x * 32, r0 = blockIdx.y * 32;
  const int tx = threadIdx.x, ty = threadIdx.y;  // 32 x 8
#pragma unroll
  for (int i = 0; i < 32; i += 8)
    t[ty + i][tx] = f2b(in[(size_t)(r0 + ty + i) * C + c0 + tx]);
  __syncthreads();
#pragma unroll
  for (int i = 0; i < 32; i += 8)
    out[(size_t)(c0 + ty + i) * R + r0 + tx] = t[tx][ty + i];
}

// ---------------- row softmax over Nn bf16 cols, in place -------------------
__global__ __launch_bounds__(256) void softmax_bf(u16* __restrict__ S) {
  u16* p = S + (size_t)blockIdx.x * Nn;
  const int tid = threadIdx.x;
  float vals[16];
  float m = -INFINITY;
#pragma unroll
  for (int i = 0; i < 16; ++i) {
    vals[i] = b2f(p[tid + i * 256]);
    m = fmaxf(m, vals[i]);
  }
#pragma unroll
  for (int off = 32; off >= 1; off >>= 1) m = fmaxf(m, __shfl_xor(m, off, 64));
  __shared__ float red[8];
  if ((tid & 63) == 0) red[tid >> 6] = m;
  __syncthreads();
  m = fmaxf(fmaxf(red[0], red[1]), fmaxf(red[2], red[3]));
  float s = 0.f;
#pragma unroll
  for (int i = 0; i < 16; ++i) {
    vals[i] = __expf(vals[i] - m);
    s += vals[i];
  }
#pragma unroll
  for (int off = 32; off >= 1; off >>= 1) s += __shfl_xor(s, off, 64);
  if ((tid & 63) == 0) red[4 + (tid >> 6)] = s;
  __syncthreads();
  s = red[4] + red[5] + red[6] + red[7];
  const float inv = 1.0f / s;
#pragma unroll
  for (int i = 0; i < 16; ++i) p[tid + i * 256] = f2b(vals[i] * inv);
}

// ---------------- GroupNorm ------------------------------------------------
__global__ __launch_bounds__(256) void gn_stats(const float* __restrict__ x,
                                                float* __restrict__ partials) {
  const int s = blockIdx.x % GN_SPLIT;
  const int bg = blockIdx.x / GN_SPLIT;
  const int b = bg / GROUPS, g = bg % GROUPS;
  const int rows = Nn / GN_SPLIT;  // 512
  const float* base = x + (size_t)b * Nn * Cc + g * CG;
  float sum = 0.f, sq = 0.f;
  for (int i = threadIdx.x; i < rows * CG; i += 256) {
    const int r = i / CG, c = i % CG;
    const float v = base[(size_t)(s * rows + r) * Cc + c];
    sum += v; sq += v * v;
  }
#pragma unroll
  for (int off = 32; off >= 1; off >>= 1) {
    sum += __shfl_xor(sum, off, 64);
    sq += __shfl_xor(sq, off, 64);
  }
  __shared__ float rs[4], rq[4];
  const int tid = threadIdx.x;
  if ((tid & 63) == 0) { rs[tid >> 6] = sum; rq[tid >> 6] = sq; }
  __syncthreads();
  if (tid == 0) {
    partials[(bg * GN_SPLIT + s) * 2 + 0] = rs[0] + rs[1] + rs[2] + rs[3];
    partials[(bg * GN_SPLIT + s) * 2 + 1] = rq[0] + rq[1] + rq[2] + rq[3];
  }
}

__global__ __launch_bounds__(256) void gn_apply(
    const float* __restrict__ x, const float* __restrict__ partials,
    const float* __restrict__ gamma, const float* __restrict__ beta,
    float* __restrict__ xn, u16* __restrict__ xnb) {
  const size_t idx = (size_t)blockIdx.x * 256 + threadIdx.x;
  const int c = (int)(idx % Cc);
  const size_t row = idx / Cc;
  const int b = (int)(row / Nn);
  const int bg = b * GROUPS + c / CG;
  float sum = 0.f, sq = 0.f;
#pragma unroll
  for (int s = 0; s < GN_SPLIT; ++s) {
    sum += partials[(bg * GN_SPLIT + s) * 2 + 0];
    sq += partials[(bg * GN_SPLIT + s) * 2 + 1];
  }
  const float cnt = (float)Nn * CG;
  const float mean = sum / cnt;
  const float var = sq / cnt - mean * mean;
  const float r = rsqrtf(var + EPS);
  const float v = (x[idx] - mean) * r * gamma[c] + beta[c];
  xn[idx] = v;
  xnb[idx] = f2b(v);
}

// ---------------- GEGLU combine: ff = g1 * qgelu(g2) ------------------------
__global__ __launch_bounds__(256) void geglu_comb(const u16* __restrict__ g1,
                                                  const u16* __restrict__ g2,
                                                  u16* __restrict__ ff) {
  const size_t i = ((size_t)blockIdx.x * 256 + threadIdx.x) * 4;
  const ushort4 a = *reinterpret_cast<const ushort4*>(g1 + i);
  const ushort4 b = *reinterpret_cast<const ushort4*>(g2 + i);
  ushort4 o;
  float v1, v2;
  v1 = b2f(a.x); v2 = b2f(b.x);
  o.x = f2b(v1 * (v2 / (1.0f + __expf(-1.702f * v2))));
  v1 = b2f(a.y); v2 = b2f(b.y);
  o.y = f2b(v1 * (v2 / (1.0f + __expf(-1.702f * v2))));
  v1 = b2f(a.z); v2 = b2f(b.z);
  o.z = f2b(v1 * (v2 / (1.0f + __expf(-1.702f * v2))));
  v1 = b2f(a.w); v2 = b2f(b.w);
  o.w = f2b(v1 * (v2 / (1.0f + __expf(-1.702f * v2))));
  *reinterpret_cast<ushort4*>(ff + i) = o;
}

// ---------------------------------------------------------------------------
extern "C" void kernel_launch(void* const* d_in, const int* in_sizes, int n_in,
                              void* d_out, int out_size, void* d_ws,
                              size_t ws_size, hipStream_t stream) {
  const float* x   = (const float*)d_in[0];
  const float* ctx = (const float*)d_in[1];
  const float* W[8];
  const float* Bv[8];
  for (int i = 0; i < 8; ++i) {
    W[i]  = (const float*)d_in[2 + 2 * i];
    Bv[i] = (const float*)d_in[3 + 2 * i];
  }
  const float* gn_g = (const float*)d_in[18];
  const float* gn_b = (const float*)d_in[19];
  const float* gw   = (const float*)d_in[20];
  const float* gb   = (const float*)d_in[21];
  const float* dw   = (const float*)d_in[22];
  const float* db   = (const float*)d_in[23];
  float* out = (float*)d_out;

  // ---- workspace layout (bytes, 256-aligned) ----
  char* base = (char*)d_ws;
  size_t o = 0;
  auto alloc = [&](size_t bytes) {
    void* p = base + o;
    o = (o + bytes + 255) & ~(size_t)255;
    return p;
  };
  u16* wT[8];
  for (int i = 0; i < 8; ++i) wT[i] = (u16*)alloc(320 * 320 * 2);
  u16* gwT  = (u16*)alloc((size_t)2560 * 320 * 2);
  u16* dwT  = (u16*)alloc((size_t)320 * 1280 * 2);
  u16* xb   = (u16*)alloc((size_t)Mm * Cc * 2);
  u16* ctxb = (u16*)alloc((size_t)Mm * Cc * 2);
  float* x2 = (float*)alloc((size_t)Mm * Cc * 4);
  float* xn = (float*)alloc((size_t)Mm * Cc * 4);
  u16* xnb  = (u16*)alloc((size_t)Mm * Cc * 2);
  float* x3 = (float*)alloc((size_t)Mm * Cc * 4);
  u16* x3b  = (u16*)alloc((size_t)Mm * Cc * 2);
  float* stats = (float*)alloc(4096);
  char* SCR = (char*)alloc((size_t)66 * 1024 * 1024);
  u16* qb   = (u16*)SCR;                 //  5.24 MB
  u16* kb   = (u16*)(SCR + 5242880);     //  5.24 MB
  float* vf = (float*)(SCR + 10485760);  // 10.49 MB
  u16* vtb  = (u16*)(SCR + 20971520);    //  5.24 MB
  u16* ob   = (u16*)(SCR + 26214400);    //  5.24 MB
  u16* Sb   = (u16*)(SCR + 31457280);    // 33.55 MB (2*2048*4096 bf16)
  // FFN aliases — everything in SCR is dead once x3 is computed
  u16* g1b = (u16*)SCR;
  u16* g2b = (u16*)(SCR + 20971520);
  u16* ffb = (u16*)(SCR + 41943040);

  if (base == nullptr || ws_size < o) return;  // d_out stays poisoned

  const float scale = 1.0f / sqrtf((float)Cc);
  const long long NC = (long long)Nn * Cc;

  auto gemm_b = [&](const u16* A, int lda, long long aZ, const u16* B, int ldb,
                    long long bZ, const float* bias, u16* C, int ldc,
                    long long cZ, int Mr, int Nc, int K, float sc, int nz) {
    dim3 grid(Nc / 64, Mr / 128, nz);
    gemm_nt<false, false><<<grid, 256, 0, stream>>>(
        A, lda, aZ, B, ldb, bZ, bias, nullptr, 0.f, nullptr, C, ldc, cZ,
        nullptr, K, sc);
  };
  auto gemm_f = [&](const u16* A, int lda, const u16* B, int ldb,
                    const float* bias, const float* R1, float a1,
                    const float* R2, float* C, int ldc, int Mr, int Nc, int K) {
    dim3 grid(Nc / 64, Mr / 128, 1);
    gemm_nt<true, false><<<grid, 256, 0, stream>>>(
        A, lda, 0, B, ldb, 0, bias, R1, a1, R2, C, ldc, 0, nullptr, K, 1.f);
  };

  // ---- cast inputs & transpose weights (every call; ws is re-poisoned) ----
  cast_b<<<(Mm * Cc) / 1024, 256, 0, stream>>>(x, xb);
  cast_b<<<(Mm * Cc) / 1024, 256, 0, stream>>>(ctx, ctxb);
  for (int i = 0; i < 8; ++i)
    tran_f2b<<<dim3(10, 10, 1), dim3(32, 8), 0, stream>>>(W[i], wT[i], 320, 320, 0, 0);
  tran_f2b<<<dim3(80, 10, 1), dim3(32, 8), 0, stream>>>(gw, gwT, 320, 2560, 0, 0);
  tran_f2b<<<dim3(10, 40, 1), dim3(32, 8), 0, stream>>>(dw, dwT, 1280, 320, 0, 0);

  auto attention = [&](const u16* qsrc, const u16* kv, int wi) {
    gemm_b(qsrc, Cc, 0, wT[wi + 0], Cc, 0, Bv[wi + 0], qb, Cc, 0, Mm, Cc, Cc, 1.f, 1);
    gemm_b(kv,   Cc, 0, wT[wi + 1], Cc, 0, Bv[wi + 1], kb, Cc, 0, Mm, Cc, Cc, 1.f, 1);
    {
      dim3 grid(Cc / 64, Mm / 128, 1);
      gemm_nt<true, false><<<grid, 256, 0, stream>>>(
          kv, Cc, 0, wT[wi + 2], Cc, 0, Bv[wi + 2], nullptr, 0.f, nullptr, vf,
          Cc, 0, nullptr, Cc, 1.f);
    }
    tran_f2b<<<dim3(Cc / 32, Nn / 32, 2), dim3(32, 8), 0, stream>>>(
        vf, vtb, Nn, Cc, NC, NC);
    for (int ch = 0; ch < Nn / CH; ++ch) {
      gemm_b(qb + (size_t)ch * CH * Cc, Cc, NC, kb, Cc, NC, nullptr, Sb, Nn,
             (long long)CH * Nn, CH, Nn, Cc, scale, 2);
      softmax_bf<<<2 * CH, 256, 0, stream>>>(Sb);
      gemm_b(Sb, Nn, (long long)CH * Nn, vtb, Nn, NC, nullptr,
             ob + (size_t)ch * CH * Cc, Cc, NC, CH, Cc, Nn, 1.f, 2);
    }
  };

  // ---- self-attention: x2 = o@Wp + bp + 2*x ----
  attention(xb, xb, 0);
  gemm_f(ob, Cc, wT[3], Cc, Bv[3], x, 2.0f, nullptr, x2, Cc, Mm, Cc, Cc);

  // ---- GroupNorm(x2) -> xn (fp32) + xnb (bf16) ----
  gn_stats<<<Bb * GROUPS * GN_SPLIT, 256, 0, stream>>>(x2, stats);
  gn_apply<<<(Mm * Cc) / 256, 256, 0, stream>>>(x2, stats, gn_g, gn_b, xn, xnb);

  // ---- cross-attention: x3 = o@Wp2 + bp2 + xn + x2 (fp32 + bf16 dual) ----
  attention(xnb, ctxb, 4);
  {
    dim3 grid(Cc / 64, Mm / 128, 1);
    gemm_nt<true, true><<<grid, 256, 0, stream>>>(
        ob, Cc, 0, wT[7], Cc, 0, Bv[7], xn, 1.0f, x2, x3, Cc, 0, x3b, Cc, 1.f);
  }

  // ---- GEGLU FFN ----
  gemm_b(x3b, Cc, 0, gwT, Cc, 0, gb, g1b, 1280, 0, Mm, 1280, Cc, 1.f, 1);
  gemm_b(x3b, Cc, 0, gwT + (size_t)1280 * 320, Cc, 0, gb + 1280, g2b, 1280, 0,
         Mm, 1280, Cc, 1.f, 1);
  geglu_comb<<<(int)(((size_t)Mm * 1280) / 1024), 256, 0, stream>>>(g1b, g2b, ffb);
  gemm_f(ffb, 1280, dwT, 1280, db, x3, 1.0f, nullptr, out, Cc, Mm, Cc, 1280);
}